// Round 2
// baseline (59.534 us; speedup 1.0000x reference)
//
#include <hip/hip_runtime.h>

typedef float v4f __attribute__((ext_vector_type(4)));

// ---------------------------------------------------------------------------
// LivingLooper forward, 2 dispatches:
//  Kernel A: fused x=tanh((window-center)/2) -> per-block matvec partials
//            (written to ws, no atomics/no memset) + grid-stride mem2 copy
//            (with ring-buffer overrides) + audio crossfade.
//  Kernel B: reduce partials over chunks, bias + target_process_inv + clip,
//            write zs and mem2[record_index].
// Outputs concatenated: y [L*BLK], zs [L*D], mem2 [M*L*D]
// ---------------------------------------------------------------------------

__global__ __launch_bounds__(256) void ll_main_kernel(
    const float* __restrict__ memory, const float* __restrict__ z_in,
    const float* __restrict__ weights, const float* __restrict__ center,
    const float* __restrict__ mask, const float* __restrict__ y_audio,
    const int* __restrict__ rec_p, const int* __restrict__ act_p,
    const int* __restrict__ lc_p, const int* __restrict__ ctx_p,
    float* __restrict__ partials, float* __restrict__ out_y,
    float* __restrict__ out_mem2,
    int L, int D, int F, int n_memory, int blocksPerLoop, int BLK)
{
    __shared__ float x_lds[256];
    __shared__ float ps[8 * 128];

    const int bid = blockIdx.x;
    const int l = bid / blocksPerLoop;
    const int chunk = bid - l * blocksPerLoop;
    const int f0 = chunk * 256;
    const int tid = threadIdx.x;

    const int rec = *rec_p;
    const int i_act = *act_p - 1;
    const int lc = *lc_p;
    const int ctx = *ctx_p;
    const int LD = L * D;

    // ---- x[f0 .. f0+255] into LDS ----
    {
        const int f = f0 + tid;
        const int c = f / LD;          // context index
        const int rem = f - c * LD;
        const int ll = rem / D;
        const int dd = rem - ll * D;
        int row = rec - ctx + c;
        row %= n_memory; if (row < 0) row += n_memory;
        int diff = rec - row; if (diff < 0) diff += n_memory;
        float v = (ll == i_act && diff <= lc)
                      ? z_in[dd]
                      : memory[(size_t)row * LD + rem];
        const float cen = center[(size_t)l * F + f];
        x_lds[tid] = tanhf((v - cen) * 0.5f);
    }
    __syncthreads();

    // ---- matvec: 8 groups of 32 lanes; group g does rows g, g+8, ... ----
    const int g = tid >> 5;
    const int t = tid & 31;
    const v4f* __restrict__ W = (const v4f*)(weights + ((size_t)l * F + f0) * D);
    v4f acc = (v4f)0.f;
    #pragma unroll 8
    for (int i = 0; i < 32; ++i) {
        const int r = i * 8 + g;
        const float xv = x_lds[r];                       // LDS broadcast
        const v4f w = __builtin_nontemporal_load(&W[(size_t)r * 32 + t]);
        acc += xv * w;                                   // 4 fp32 FMA
    }
    ((v4f*)&ps[g * 128])[t] = acc;
    __syncthreads();

    if (tid < 128) {
        float s = 0.f;
        #pragma unroll
        for (int gg = 0; gg < 8; ++gg) s += ps[gg * 128 + tid];
        partials[(size_t)bid * 128 + tid] = s;           // coalesced 512B/block
    }

    // ---- fused misc work: mem2 copy (except row rec) + audio fade ----
    const int gsize = gridDim.x * 256;
    const int Ncopy = n_memory * LD;
    const int total = Ncopy + L * BLK;
    for (int idx = bid * 256 + tid; idx < total; idx += gsize) {
        if (idx < Ncopy) {
            const int row = idx / LD;
            if (row == rec) continue;      // finalize kernel owns this row
            const int rem = idx - row * LD;
            const int ll = rem / D;
            const int dd = rem - ll * D;
            int diff = rec - row; if (diff < 0) diff += n_memory;
            const float v = (ll == i_act && diff <= lc) ? z_in[dd] : memory[idx];
            __builtin_nontemporal_store(v, &out_mem2[idx]);
        } else {
            const int j = idx - Ncopy;
            const int li = j / BLK;
            const int k = j - li * BLK;
            const float fade = (float)k / (float)(BLK - 1);
            const float m = mask[L + li] * fade + mask[li] * (1.f - fade);
            out_y[j] = y_audio[j] * m;
        }
    }
}

// reduce partials; bias, target_process_inv, clip; write zs and mem2[rec].
__global__ __launch_bounds__(256) void ll_finalize_kernel(
    const float* __restrict__ partials, const float* __restrict__ bias,
    const float* __restrict__ z_min, const float* __restrict__ z_max,
    const float* __restrict__ limit_margin, const float* __restrict__ z_in,
    const int* __restrict__ rec_p, const int* __restrict__ act_p,
    float* __restrict__ out_zs, float* __restrict__ out_mem2,
    int L, int D, int blocksPerLoop)
{
    const int tid = blockIdx.x * blockDim.x + threadIdx.x;
    if (tid >= L * D) return;
    const int l = tid / D;
    const int d = tid - l * D;

    float s = 0.f;
    const float* __restrict__ p = partials + (size_t)l * blocksPerLoop * D + d;
    #pragma unroll 8
    for (int c = 0; c < blocksPerLoop; ++c)      // coalesced across threads
        s += p[(size_t)c * D];

    float z = s + bias[tid];
    const float hi = 2.f * sqrtf(fmaxf(z, 1.f)) - 1.f;
    const float lo = 1.f - 2.f * sqrtf(fmaxf(-z, 1.f));
    z = (z > 1.f) ? hi : ((z < -1.f) ? lo : z);
    const float zl = z_min[tid] - limit_margin[d];
    const float zh = z_max[tid] + limit_margin[d];
    z = fminf(fmaxf(z, zl), zh);

    const float out = (l == (*act_p - 1)) ? z_in[d] : z;
    out_zs[tid] = out;
    out_mem2[(size_t)(*rec_p) * (L * D) + tid] = out;
}

extern "C" void kernel_launch(void* const* d_in, const int* in_sizes, int n_in,
                              void* d_out, int out_size, void* d_ws, size_t ws_size,
                              hipStream_t stream) {
    const float* memory       = (const float*)d_in[0];
    const float* z_in         = (const float*)d_in[1];
    const float* weights      = (const float*)d_in[2];
    const float* center       = (const float*)d_in[3];
    const float* bias         = (const float*)d_in[4];
    const float* z_min        = (const float*)d_in[5];
    const float* z_max        = (const float*)d_in[6];
    const float* limit_margin = (const float*)d_in[7];
    const float* mask         = (const float*)d_in[8];
    const float* y_audio      = (const float*)d_in[9];
    const int*   rec_p        = (const int*)d_in[10];
    const int*   act_p        = (const int*)d_in[11];
    const int*   lc_p         = (const int*)d_in[12];
    const int*   ctx_p        = (const int*)d_in[13];

    const int D        = in_sizes[1];            // 128
    const int L        = in_sizes[4] / D;        // 8
    const int LD       = L * D;                  // 1024
    const int n_memory = in_sizes[0] / LD;       // 1067
    const int F        = in_sizes[3] / L;        // 65536
    const int BLK      = in_sizes[9] / L;        // 2048

    float* out_y    = (float*)d_out;             // [L*BLK]
    float* out_zs   = out_y + (size_t)L * BLK;   // [LD]
    float* out_mem2 = out_zs + LD;               // [n_memory*LD]

    float* partials = (float*)d_ws;              // [L*blocksPerLoop*D] = 1 MB

    const int blocksPerLoop = F / 256;           // 256
    ll_main_kernel<<<L * blocksPerLoop, 256, 0, stream>>>(
        memory, z_in, weights, center, mask, y_audio,
        rec_p, act_p, lc_p, ctx_p,
        partials, out_y, out_mem2,
        L, D, F, n_memory, blocksPerLoop, BLK);

    ll_finalize_kernel<<<(LD + 255) / 256, 256, 0, stream>>>(
        partials, bias, z_min, z_max, limit_margin, z_in,
        rec_p, act_p, out_zs, out_mem2, L, D, blocksPerLoop);
}

// Round 3
// 58.005 us; speedup vs baseline: 1.0264x; 1.0264x over previous
//
#include <hip/hip_runtime.h>

typedef float v4f __attribute__((ext_vector_type(4)));

// ---------------------------------------------------------------------------
// LivingLooper forward, 2 dispatches.
//  A: prologue-prefetched, blocked-row matvec (x=tanh((win-center)/2) in LDS,
//     weights streamed with immediate-offset float4 loads) + float4 grid-stride
//     mem2 copy (ring overrides) + float4 audio crossfade.
//  B: reduce per-block partials, bias + target_process_inv + clip, write zs
//     and mem2[record_index].
// Outputs concatenated: y [L*BLK], zs [L*D], mem2 [M*L*D]
// ---------------------------------------------------------------------------

__global__ __launch_bounds__(256) void ll_main_kernel(
    const float* __restrict__ memory, const float* __restrict__ z_in,
    const float* __restrict__ weights, const float* __restrict__ center,
    const float* __restrict__ mask, const float* __restrict__ y_audio,
    const int* __restrict__ rec_p, const int* __restrict__ act_p,
    const int* __restrict__ lc_p, const int* __restrict__ ctx_p,
    float* __restrict__ partials, float* __restrict__ out_y,
    float* __restrict__ out_mem2,
    int L, int F, int n_memory, int blocksPerLoop, int BLK,
    int Dsh, int LDsh, int BLKsh)
{
    __shared__ float x_lds[256];
    __shared__ float ps[8 * 128];

    const int D  = 1 << Dsh;
    const int LD = 1 << LDsh;

    const int bid = blockIdx.x;
    const int l = bid / blocksPerLoop;
    const int chunk = bid - l * blocksPerLoop;
    const int f0 = chunk * 256;
    const int tid = threadIdx.x;
    const int g = tid >> 5;          // 8 row-groups
    const int t = tid & 31;          // lane within group: d-range t*4..t*4+3

    const int rec = *rec_p;
    const int i_act = *act_p - 1;
    const int lc = *lc_p;
    const int ctx = *ctx_p;

    // ---- prologue prefetch: batch 0 (rows g*32 .. g*32+7), imm offsets ----
    const v4f* __restrict__ Wv =
        (const v4f*)(weights + (((size_t)(l * F + f0) + (g << 5)) << Dsh)) + t;
    v4f pre[8];
    #pragma unroll
    for (int j = 0; j < 8; ++j) pre[j] = Wv[j << 5];   // j*512B

    // ---- x[f0 .. f0+255] into LDS (overlaps with prefetch latency) ----
    {
        const int f = f0 + tid;
        const int c = f >> LDsh;
        const int rem = f & (LD - 1);
        const int ll = rem >> Dsh;
        const int dd = rem & (D - 1);
        int row = rec - ctx + c;
        if (row < 0) row += n_memory;
        const int dt = ctx - c;                  // true ring distance, 1..ctx
        const float v = (ll == i_act && dt <= lc)
                            ? z_in[dd]
                            : memory[((size_t)row << LDsh) + rem];
        const float cen = center[(size_t)l * F + f];
        x_lds[tid] = tanhf((v - cen) * 0.5f);
    }
    __syncthreads();

    // ---- matvec: group g owns contiguous rows [g*32, g*32+32) ----
    v4f acc = (v4f)0.f;
    #pragma unroll
    for (int j = 0; j < 8; ++j) acc += x_lds[(g << 5) + j] * pre[j];
    #pragma unroll 8
    for (int i = 8; i < 32; ++i)
        acc += x_lds[(g << 5) + i] * Wv[i << 5];

    ((v4f*)&ps[g << 7])[t] = acc;
    __syncthreads();

    if (tid < 128) {
        float s = 0.f;
        #pragma unroll
        for (int gg = 0; gg < 8; ++gg) s += ps[(gg << 7) + tid];
        partials[((size_t)bid << 7) + tid] = s;          // coalesced
    }

    // ---- fused misc: float4 mem2 copy (except row rec) + audio fade ----
    const int gsize = gridDim.x * 256;
    const int Ncopy4 = (n_memory << LDsh) >> 2;
    const int total4 = Ncopy4 + ((L * BLK) >> 2);
    for (int i4 = bid * 256 + tid; i4 < total4; i4 += gsize) {
        if (i4 < Ncopy4) {
            const int idx = i4 << 2;
            const int row = idx >> LDsh;
            if (row == rec) continue;          // finalize owns this row
            const int rem = idx & (LD - 1);
            const int ll = rem >> Dsh;
            const int dd = rem & (D - 1);
            int diff = rec - row; if (diff < 0) diff += n_memory;
            v4f v;
            if (ll == i_act && diff <= lc) v = *(const v4f*)(z_in + dd);
            else                           v = *(const v4f*)(memory + idx);
            __builtin_nontemporal_store(v, (v4f*)(out_mem2 + idx));
        } else {
            const int j = (i4 - Ncopy4) << 2;
            const int li = j >> BLKsh;
            const int k = j & ((1 << BLKsh) - 1);
            const float inv = 1.f / (float)((1 << BLKsh) - 1);
            const float m0 = mask[li], m1 = mask[L + li];
            const v4f ya = *(const v4f*)(y_audio + j);
            v4f r;
            #pragma unroll
            for (int e = 0; e < 4; ++e) {
                const float fade = (float)(k + e) * inv;
                r[e] = ya[e] * (m1 * fade + m0 * (1.f - fade));
            }
            *(v4f*)(out_y + j) = r;
        }
    }
}

// reduce partials; bias, target_process_inv, clip; write zs and mem2[rec].
__global__ __launch_bounds__(256) void ll_finalize_kernel(
    const float* __restrict__ partials, const float* __restrict__ bias,
    const float* __restrict__ z_min, const float* __restrict__ z_max,
    const float* __restrict__ limit_margin, const float* __restrict__ z_in,
    const int* __restrict__ rec_p, const int* __restrict__ act_p,
    float* __restrict__ out_zs, float* __restrict__ out_mem2,
    int L, int D, int blocksPerLoop)
{
    const int tid = blockIdx.x * blockDim.x + threadIdx.x;
    if (tid >= L * D) return;
    const int l = tid / D;
    const int d = tid - l * D;

    float s = 0.f;
    const float* __restrict__ p = partials + ((size_t)l * blocksPerLoop) * D + d;
    #pragma unroll 8
    for (int c = 0; c < blocksPerLoop; ++c)      // coalesced across threads
        s += p[(size_t)c * D];

    float z = s + bias[tid];
    const float hi = 2.f * sqrtf(fmaxf(z, 1.f)) - 1.f;
    const float lo = 1.f - 2.f * sqrtf(fmaxf(-z, 1.f));
    z = (z > 1.f) ? hi : ((z < -1.f) ? lo : z);
    const float zl = z_min[tid] - limit_margin[d];
    const float zh = z_max[tid] + limit_margin[d];
    z = fminf(fmaxf(z, zl), zh);

    const float out = (l == (*act_p - 1)) ? z_in[d] : z;
    out_zs[tid] = out;
    out_mem2[(size_t)(*rec_p) * (L * D) + tid] = out;
}

extern "C" void kernel_launch(void* const* d_in, const int* in_sizes, int n_in,
                              void* d_out, int out_size, void* d_ws, size_t ws_size,
                              hipStream_t stream) {
    const float* memory       = (const float*)d_in[0];
    const float* z_in         = (const float*)d_in[1];
    const float* weights      = (const float*)d_in[2];
    const float* center       = (const float*)d_in[3];
    const float* bias         = (const float*)d_in[4];
    const float* z_min        = (const float*)d_in[5];
    const float* z_max        = (const float*)d_in[6];
    const float* limit_margin = (const float*)d_in[7];
    const float* mask         = (const float*)d_in[8];
    const float* y_audio      = (const float*)d_in[9];
    const int*   rec_p        = (const int*)d_in[10];
    const int*   act_p        = (const int*)d_in[11];
    const int*   lc_p         = (const int*)d_in[12];
    const int*   ctx_p        = (const int*)d_in[13];

    const int D        = in_sizes[1];            // 128
    const int L        = in_sizes[4] / D;        // 8
    const int LD       = L * D;                  // 1024
    const int n_memory = in_sizes[0] / LD;       // 1067
    const int F        = in_sizes[3] / L;        // 65536
    const int BLK      = in_sizes[9] / L;        // 2048

    const int Dsh   = __builtin_ctz(D);          // 7
    const int LDsh  = __builtin_ctz(LD);         // 10
    const int BLKsh = __builtin_ctz(BLK);        // 11

    float* out_y    = (float*)d_out;             // [L*BLK]
    float* out_zs   = out_y + (size_t)L * BLK;   // [LD]
    float* out_mem2 = out_zs + LD;               // [n_memory*LD]

    float* partials = (float*)d_ws;              // [L*blocksPerLoop*D] = 1 MB

    const int blocksPerLoop = F / 256;           // 256
    ll_main_kernel<<<L * blocksPerLoop, 256, 0, stream>>>(
        memory, z_in, weights, center, mask, y_audio,
        rec_p, act_p, lc_p, ctx_p,
        partials, out_y, out_mem2,
        L, F, n_memory, blocksPerLoop, BLK, Dsh, LDsh, BLKsh);

    ll_finalize_kernel<<<(LD + 255) / 256, 256, 0, stream>>>(
        partials, bias, z_min, z_max, limit_margin, z_in,
        rec_p, act_p, out_zs, out_mem2, L, D, blocksPerLoop);
}

// Round 4
// 54.656 us; speedup vs baseline: 1.0893x; 1.0613x over previous
//
#include <hip/hip_runtime.h>

typedef float v4f __attribute__((ext_vector_type(4)));

// ---------------------------------------------------------------------------
// LivingLooper forward, 2 dispatches.
//  A: blocked matvec with WAVE-CONTIGUOUS weight streaming: wave w owns rows
//     [w*64, w*64+64); iteration i loads rows w*64+2i (lanes 0-31) and
//     w*64+2i+1 (lanes 32-63) -> one aligned 1 KiB segment per instruction.
//     + fused float4 mem2 copy (ring overrides) + float4 audio crossfade.
//  B: reduce per-block partials, bias + target_process_inv + clip, write zs
//     and mem2[record_index].
// Outputs concatenated: y [L*BLK], zs [L*D], mem2 [M*L*D]
// ---------------------------------------------------------------------------

__global__ __launch_bounds__(256) void ll_main_kernel(
    const float* __restrict__ memory, const float* __restrict__ z_in,
    const float* __restrict__ weights, const float* __restrict__ center,
    const float* __restrict__ mask, const float* __restrict__ y_audio,
    const int* __restrict__ rec_p, const int* __restrict__ act_p,
    const int* __restrict__ lc_p, const int* __restrict__ ctx_p,
    float* __restrict__ partials, float* __restrict__ out_y,
    float* __restrict__ out_mem2,
    int L, int F, int n_memory, int blocksPerLoop, int BLK,
    int Dsh, int LDsh, int BLKsh)
{
    __shared__ float x_lds[256];
    __shared__ float ps[8 * 128];

    const int D  = 1 << Dsh;
    const int LD = 1 << LDsh;

    const int bid = blockIdx.x;
    const int l = bid / blocksPerLoop;
    const int chunk = bid - l * blocksPerLoop;
    const int f0 = chunk * 256;
    const int tid = threadIdx.x;
    const int w = tid >> 6;          // wave 0..3: owns rows [w*64, w*64+64)
    const int p = (tid >> 5) & 1;    // half-wave parity (even/odd row)
    const int t = tid & 31;          // lane in half: d-range t*4..t*4+3
    const int rbase = (w << 6) + p;  // row for i=0

    const int rec = *rec_p;
    const int i_act = *act_p - 1;
    const int lc = *lc_p;
    const int ctx = *ctx_p;

    // Wv: iteration i reads Wv[i<<6] -> rows rbase+2i; per-wave footprint of
    // one instruction = 64 lanes * 16B = 1 KiB contiguous & aligned.
    const v4f* __restrict__ Wv =
        (const v4f*)(weights + ((size_t)(l * F + f0) << Dsh)) + (rbase << 5) + t;

    // ---- prologue prefetch: first 8 iterations (imm offsets, 1 KiB apart) --
    v4f pre[8];
    #pragma unroll
    for (int j = 0; j < 8; ++j) pre[j] = Wv[j << 6];

    // ---- x[f0 .. f0+255] into LDS (overlaps prefetch latency) ----
    {
        const int f = f0 + tid;
        const int c = f >> LDsh;
        const int rem = f & (LD - 1);
        const int ll = rem >> Dsh;
        const int dd = rem & (D - 1);
        int row = rec - ctx + c;
        if (row < 0) row += n_memory;
        const int dt = ctx - c;                  // ring distance, 1..ctx
        const float v = (ll == i_act && dt <= lc)
                            ? z_in[dd]
                            : memory[((size_t)row << LDsh) + rem];
        const float cen = center[(size_t)l * F + f];
        x_lds[tid] = tanhf((v - cen) * 0.5f);
    }
    __syncthreads();

    // ---- matvec ----
    v4f acc = (v4f)0.f;
    #pragma unroll
    for (int j = 0; j < 8; ++j) acc += x_lds[rbase + (j << 1)] * pre[j];
    #pragma unroll 8
    for (int i = 8; i < 32; ++i)
        acc += x_lds[rbase + (i << 1)] * Wv[i << 6];

    // group g = tid>>5 = w*2+p accumulated rows {w*64 + 2i + p}; union = all.
    ((v4f*)&ps[(tid >> 5) << 7])[t] = acc;
    __syncthreads();

    if (tid < 128) {
        float s = 0.f;
        #pragma unroll
        for (int gg = 0; gg < 8; ++gg) s += ps[(gg << 7) + tid];
        partials[((size_t)bid << 7) + tid] = s;          // coalesced
    }

    // ---- fused misc: float4 mem2 copy (except row rec) + audio fade ----
    const int gsize = gridDim.x * 256;
    const int Ncopy4 = (n_memory << LDsh) >> 2;
    const int total4 = Ncopy4 + ((L * BLK) >> 2);
    for (int i4 = bid * 256 + tid; i4 < total4; i4 += gsize) {
        if (i4 < Ncopy4) {
            const int idx = i4 << 2;
            const int row = idx >> LDsh;
            if (row == rec) continue;          // finalize owns this row
            const int rem = idx & (LD - 1);
            const int ll = rem >> Dsh;
            const int dd = rem & (D - 1);
            int diff = rec - row; if (diff < 0) diff += n_memory;
            v4f v;
            if (ll == i_act && diff <= lc) v = *(const v4f*)(z_in + dd);
            else                           v = *(const v4f*)(memory + idx);
            __builtin_nontemporal_store(v, (v4f*)(out_mem2 + idx));
        } else {
            const int j = (i4 - Ncopy4) << 2;
            const int li = j >> BLKsh;
            const int k = j & ((1 << BLKsh) - 1);
            const float inv = 1.f / (float)((1 << BLKsh) - 1);
            const float m0 = mask[li], m1 = mask[L + li];
            const v4f ya = *(const v4f*)(y_audio + j);
            v4f r;
            #pragma unroll
            for (int e = 0; e < 4; ++e) {
                const float fade = (float)(k + e) * inv;
                r[e] = ya[e] * (m1 * fade + m0 * (1.f - fade));
            }
            *(v4f*)(out_y + j) = r;
        }
    }
}

// reduce partials; bias, target_process_inv, clip; write zs and mem2[rec].
__global__ __launch_bounds__(256) void ll_finalize_kernel(
    const float* __restrict__ partials, const float* __restrict__ bias,
    const float* __restrict__ z_min, const float* __restrict__ z_max,
    const float* __restrict__ limit_margin, const float* __restrict__ z_in,
    const int* __restrict__ rec_p, const int* __restrict__ act_p,
    float* __restrict__ out_zs, float* __restrict__ out_mem2,
    int L, int D, int blocksPerLoop)
{
    const int tid = blockIdx.x * blockDim.x + threadIdx.x;
    if (tid >= L * D) return;
    const int l = tid / D;
    const int d = tid - l * D;

    float s = 0.f;
    const float* __restrict__ p = partials + ((size_t)l * blocksPerLoop) * D + d;
    #pragma unroll 16
    for (int c = 0; c < blocksPerLoop; ++c)      // coalesced across threads
        s += p[(size_t)c * D];

    float z = s + bias[tid];
    const float hi = 2.f * sqrtf(fmaxf(z, 1.f)) - 1.f;
    const float lo = 1.f - 2.f * sqrtf(fmaxf(-z, 1.f));
    z = (z > 1.f) ? hi : ((z < -1.f) ? lo : z);
    const float zl = z_min[tid] - limit_margin[d];
    const float zh = z_max[tid] + limit_margin[d];
    z = fminf(fmaxf(z, zl), zh);

    const float out = (l == (*act_p - 1)) ? z_in[d] : z;
    out_zs[tid] = out;
    out_mem2[(size_t)(*rec_p) * (L * D) + tid] = out;
}

extern "C" void kernel_launch(void* const* d_in, const int* in_sizes, int n_in,
                              void* d_out, int out_size, void* d_ws, size_t ws_size,
                              hipStream_t stream) {
    const float* memory       = (const float*)d_in[0];
    const float* z_in         = (const float*)d_in[1];
    const float* weights      = (const float*)d_in[2];
    const float* center       = (const float*)d_in[3];
    const float* bias         = (const float*)d_in[4];
    const float* z_min        = (const float*)d_in[5];
    const float* z_max        = (const float*)d_in[6];
    const float* limit_margin = (const float*)d_in[7];
    const float* mask         = (const float*)d_in[8];
    const float* y_audio      = (const float*)d_in[9];
    const int*   rec_p        = (const int*)d_in[10];
    const int*   act_p        = (const int*)d_in[11];
    const int*   lc_p         = (const int*)d_in[12];
    const int*   ctx_p        = (const int*)d_in[13];

    const int D        = in_sizes[1];            // 128
    const int L        = in_sizes[4] / D;        // 8
    const int LD       = L * D;                  // 1024
    const int n_memory = in_sizes[0] / LD;       // 1067
    const int F        = in_sizes[3] / L;        // 65536
    const int BLK      = in_sizes[9] / L;        // 2048

    const int Dsh   = __builtin_ctz(D);          // 7
    const int LDsh  = __builtin_ctz(LD);         // 10
    const int BLKsh = __builtin_ctz(BLK);        // 11

    float* out_y    = (float*)d_out;             // [L*BLK]
    float* out_zs   = out_y + (size_t)L * BLK;   // [LD]
    float* out_mem2 = out_zs + LD;               // [n_memory*LD]

    float* partials = (float*)d_ws;              // [L*blocksPerLoop*D] = 1 MB

    const int blocksPerLoop = F / 256;           // 256
    ll_main_kernel<<<L * blocksPerLoop, 256, 0, stream>>>(
        memory, z_in, weights, center, mask, y_audio,
        rec_p, act_p, lc_p, ctx_p,
        partials, out_y, out_mem2,
        L, F, n_memory, blocksPerLoop, BLK, Dsh, LDsh, BLKsh);

    ll_finalize_kernel<<<(LD + 255) / 256, 256, 0, stream>>>(
        partials, bias, z_min, z_max, limit_margin, z_in,
        rec_p, act_p, out_zs, out_mem2, L, D, blocksPerLoop);
}

// Round 7
// 53.150 us; speedup vs baseline: 1.1201x; 1.0283x over previous
//
#include <hip/hip_runtime.h>

typedef float v4f __attribute__((ext_vector_type(4)));

#define NMISC 32   // dedicated copy/fade blocks at the head of the grid

// ---------------------------------------------------------------------------
// LivingLooper forward, 2 dispatches (no cross-block sync — round-6 lesson:
// intra-dispatch cross-XCD handoff of plain stores is slow AND racy; the
// kernel boundary is the fence).
//  Kernel A (512 thr):
//   blocks [0,NMISC): float4 mem2 copy (ring overrides) + float4 audio fade.
//   blocks [NMISC,NMISC+L*bpl): matvec tiles, 512 contiguous f-rows each.
//     Wave w owns rows [w*64,w*64+64); iteration i loads rows w*64+2i (lanes
//     0-31) and w*64+2i+1 (lanes 32-63) -> one aligned 1 KiB segment per
//     instruction. x = tanh((window-center)*0.5) staged in LDS. Partials->ws.
//  Kernel B: reduce 128 chunk-partials per (l,d), bias+inv+clip, write zs and
//     mem2[record_index].
// Outputs concatenated: y [L*BLK], zs [L*D], mem2 [M*L*D]
// ---------------------------------------------------------------------------

__global__ __launch_bounds__(512) void ll_main_kernel(
    const float* __restrict__ memory, const float* __restrict__ z_in,
    const float* __restrict__ weights, const float* __restrict__ center,
    const float* __restrict__ mask, const float* __restrict__ y_audio,
    const int* __restrict__ rec_p, const int* __restrict__ act_p,
    const int* __restrict__ lc_p, const int* __restrict__ ctx_p,
    float* __restrict__ partials, float* __restrict__ out_y,
    float* __restrict__ out_mem2,
    int L, int F, int n_memory, int BLK,
    int Dsh, int LDsh, int BLKsh, int bplSh)
{
    const int D  = 1 << Dsh;
    const int LD = 1 << LDsh;
    const int bid = blockIdx.x;
    const int tid = threadIdx.x;

    const int rec = *rec_p;
    const int i_act = *act_p - 1;
    const int lc = *lc_p;

    if (bid < NMISC) {
        // ---- misc: float4 mem2 copy (except row rec) + audio fade ----
        const int gsize = NMISC * 512;
        const int Ncopy4 = (n_memory << LDsh) >> 2;
        const int total4 = Ncopy4 + ((L * BLK) >> 2);
        for (int i4 = bid * 512 + tid; i4 < total4; i4 += gsize) {
            if (i4 < Ncopy4) {
                const int idx = i4 << 2;
                const int row = idx >> LDsh;
                if (row == rec) continue;        // kernel B owns this row
                const int rem = idx & (LD - 1);
                const int ll = rem >> Dsh;
                const int dd = rem & (D - 1);
                int diff = rec - row; if (diff < 0) diff += n_memory;
                v4f v;
                if (ll == i_act && diff <= lc) v = *(const v4f*)(z_in + dd);
                else                           v = *(const v4f*)(memory + idx);
                __builtin_nontemporal_store(v, (v4f*)(out_mem2 + idx));
            } else {
                const int j = (i4 - Ncopy4) << 2;
                const int li = j >> BLKsh;
                const int k = j & ((1 << BLKsh) - 1);
                const float inv = 1.f / (float)((1 << BLKsh) - 1);
                const float m0 = mask[li], m1 = mask[L + li];
                const v4f ya = *(const v4f*)(y_audio + j);
                v4f r;
                #pragma unroll
                for (int e = 0; e < 4; ++e) {
                    const float fade = (float)(k + e) * inv;
                    r[e] = ya[e] * (m1 * fade + m0 * (1.f - fade));
                }
                *(v4f*)(out_y + j) = r;
            }
        }
        return;
    }

    // ---------------- matvec tile ----------------
    __shared__ float x_lds[512];
    __shared__ float ps[16 * 128];

    const int mb = bid - NMISC;
    const int l = mb >> bplSh;
    const int chunk = mb & ((1 << bplSh) - 1);
    const int f0 = chunk << 9;           // 512 rows per tile

    const int w = tid >> 6;              // wave 0..7: rows [w*64, w*64+64)
    const int par = (tid >> 5) & 1;      // even/odd row within pair
    const int t = tid & 31;              // lane: d-range t*4..t*4+3
    const int rbase = (w << 6) + par;

    // iteration i reads rows rbase+2i -> offset i KiB; 1 KiB/wave-instruction
    const v4f* __restrict__ Wv =
        (const v4f*)(weights + ((size_t)(l * F + f0) << Dsh)) + (rbase << 5) + t;

    v4f pre[8];
    #pragma unroll
    for (int j = 0; j < 8; ++j) pre[j] = Wv[j << 6];

    // ---- x[f0 .. f0+511] into LDS (overlaps prefetch latency) ----
    {
        const int f = f0 + tid;
        const int c = f >> LDsh;
        const int rem = f & (LD - 1);
        const int ll = rem >> Dsh;
        const int dd = rem & (D - 1);
        int row = rec - (*ctx_p) + c;
        if (row < 0) row += n_memory;
        const int dt = (*ctx_p) - c;             // ring distance, 1..ctx
        const float v = (ll == i_act && dt <= lc)
                            ? z_in[dd]
                            : memory[((size_t)row << LDsh) + rem];
        const float cen = center[(size_t)l * F + f];
        x_lds[tid] = tanhf((v - cen) * 0.5f);
    }
    __syncthreads();

    // ---- matvec ----
    v4f acc = (v4f)0.f;
    #pragma unroll
    for (int j = 0; j < 8; ++j) acc += x_lds[rbase + (j << 1)] * pre[j];
    #pragma unroll 8
    for (int i = 8; i < 32; ++i)
        acc += x_lds[rbase + (i << 1)] * Wv[i << 6];

    ((v4f*)&ps[(tid >> 5) << 7])[t] = acc;       // 16 groups x 128
    __syncthreads();

    if (tid < 128) {
        float s = 0.f;
        #pragma unroll
        for (int gg = 0; gg < 16; ++gg) s += ps[(gg << 7) + tid];
        partials[((size_t)mb << 7) + tid] = s;   // coalesced 512B
    }
}

// reduce partials; bias, target_process_inv, clip; write zs and mem2[rec].
__global__ __launch_bounds__(256) void ll_finalize_kernel(
    const float* __restrict__ partials, const float* __restrict__ bias,
    const float* __restrict__ z_min, const float* __restrict__ z_max,
    const float* __restrict__ limit_margin, const float* __restrict__ z_in,
    const int* __restrict__ rec_p, const int* __restrict__ act_p,
    float* __restrict__ out_zs, float* __restrict__ out_mem2,
    int L, int D, int bpl)
{
    const int tid = blockIdx.x * blockDim.x + threadIdx.x;
    if (tid >= L * D) return;
    const int l = tid / D;
    const int d = tid - l * D;

    float s = 0.f;
    const float* __restrict__ p = partials + ((size_t)l * bpl) * D + d;
    #pragma unroll 16
    for (int c = 0; c < bpl; ++c)        // coalesced across threads
        s += p[(size_t)c * D];

    float z = s + bias[tid];
    const float hi = 2.f * sqrtf(fmaxf(z, 1.f)) - 1.f;
    const float lo = 1.f - 2.f * sqrtf(fmaxf(-z, 1.f));
    z = (z > 1.f) ? hi : ((z < -1.f) ? lo : z);
    const float zl = z_min[tid] - limit_margin[d];
    const float zh = z_max[tid] + limit_margin[d];
    z = fminf(fmaxf(z, zl), zh);

    const float out = (l == (*act_p - 1)) ? z_in[d] : z;
    out_zs[tid] = out;
    out_mem2[(size_t)(*rec_p) * (L * D) + tid] = out;
}

extern "C" void kernel_launch(void* const* d_in, const int* in_sizes, int n_in,
                              void* d_out, int out_size, void* d_ws, size_t ws_size,
                              hipStream_t stream) {
    const float* memory       = (const float*)d_in[0];
    const float* z_in         = (const float*)d_in[1];
    const float* weights      = (const float*)d_in[2];
    const float* center       = (const float*)d_in[3];
    const float* bias         = (const float*)d_in[4];
    const float* z_min        = (const float*)d_in[5];
    const float* z_max        = (const float*)d_in[6];
    const float* limit_margin = (const float*)d_in[7];
    const float* mask         = (const float*)d_in[8];
    const float* y_audio      = (const float*)d_in[9];
    const int*   rec_p        = (const int*)d_in[10];
    const int*   act_p        = (const int*)d_in[11];
    const int*   lc_p         = (const int*)d_in[12];
    const int*   ctx_p        = (const int*)d_in[13];

    const int D        = in_sizes[1];            // 128
    const int L        = in_sizes[4] / D;        // 8
    const int LD       = L * D;                  // 1024
    const int n_memory = in_sizes[0] / LD;       // 1067
    const int F        = in_sizes[3] / L;        // 65536
    const int BLK      = in_sizes[9] / L;        // 2048

    const int Dsh   = __builtin_ctz(D);          // 7
    const int LDsh  = __builtin_ctz(LD);         // 10
    const int BLKsh = __builtin_ctz(BLK);        // 11
    const int bpl   = F >> 9;                    // 128 blocks per loop
    const int bplSh = __builtin_ctz(bpl);        // 7

    float* out_y    = (float*)d_out;             // [L*BLK]
    float* out_zs   = out_y + (size_t)L * BLK;   // [LD]
    float* out_mem2 = out_zs + LD;               // [n_memory*LD]

    float* partials = (float*)d_ws;              // [L*bpl*128] = 512 KB

    const int grid = NMISC + L * bpl;            // 32 + 1024
    ll_main_kernel<<<grid, 512, 0, stream>>>(
        memory, z_in, weights, center, mask, y_audio,
        rec_p, act_p, lc_p, ctx_p,
        partials, out_y, out_mem2,
        L, F, n_memory, BLK, Dsh, LDsh, BLKsh, bplSh);

    ll_finalize_kernel<<<(LD + 255) / 256, 256, 0, stream>>>(
        partials, bias, z_min, z_max, limit_margin, z_in,
        rec_p, act_p, out_zs, out_mem2, L, D, bpl);
}

// Round 8
// 52.977 us; speedup vs baseline: 1.1238x; 1.0033x over previous
//
#include <hip/hip_runtime.h>

typedef float v4f __attribute__((ext_vector_type(4)));

#define NMISC 256  // misc blocks; grid = 256 + 1024 = 1280 = 5*256 CUs exactly

// ---------------------------------------------------------------------------
// LivingLooper forward, 2 dispatches (kernel boundary = coherence fence; the
// round-6 intra-dispatch handoff was slow AND racy).
//  Kernel A (512 thr, grid 1280 = 5 blocks/CU exactly):
//   blocks [0,NMISC): float4 mem2 copy (ring overrides) + float4 audio fade
//     (~34 KB/block; dispatched first, finish early, release CU slots).
//   blocks [NMISC,NMISC+1024): matvec tiles, 512 contiguous f-rows each.
//     Wave w owns rows [w*64,w*64+64); iteration i loads rows w*64+2i (lanes
//     0-31) / w*64+2i+1 (lanes 32-63) -> one aligned 1 KiB segment per
//     instruction. x = tanh((window-center)*0.5) in LDS. Partials -> ws.
//  Kernel B: reduce 128 chunk-partials per (l,d) with 4-way MLP accumulators,
//     bias + target_process_inv + clip, write zs and mem2[record_index].
// Outputs concatenated: y [L*BLK], zs [L*D], mem2 [M*L*D]
// ---------------------------------------------------------------------------

__global__ __launch_bounds__(512) void ll_main_kernel(
    const float* __restrict__ memory, const float* __restrict__ z_in,
    const float* __restrict__ weights, const float* __restrict__ center,
    const float* __restrict__ mask, const float* __restrict__ y_audio,
    const int* __restrict__ rec_p, const int* __restrict__ act_p,
    const int* __restrict__ lc_p, const int* __restrict__ ctx_p,
    float* __restrict__ partials, float* __restrict__ out_y,
    float* __restrict__ out_mem2,
    int L, int F, int n_memory, int BLK,
    int Dsh, int LDsh, int BLKsh, int bplSh)
{
    const int D  = 1 << Dsh;
    const int LD = 1 << LDsh;
    const int bid = blockIdx.x;
    const int tid = threadIdx.x;

    const int rec = *rec_p;
    const int i_act = *act_p - 1;
    const int lc = *lc_p;

    if (bid < NMISC) {
        // ---- misc: float4 mem2 copy (except row rec) + audio fade ----
        const int gsize = NMISC * 512;
        const int Ncopy4 = (n_memory << LDsh) >> 2;
        const int total4 = Ncopy4 + ((L * BLK) >> 2);
        for (int i4 = bid * 512 + tid; i4 < total4; i4 += gsize) {
            if (i4 < Ncopy4) {
                const int idx = i4 << 2;
                const int row = idx >> LDsh;
                if (row == rec) continue;        // kernel B owns this row
                const int rem = idx & (LD - 1);
                const int ll = rem >> Dsh;
                const int dd = rem & (D - 1);
                int diff = rec - row; if (diff < 0) diff += n_memory;
                v4f v;
                if (ll == i_act && diff <= lc) v = *(const v4f*)(z_in + dd);
                else                           v = *(const v4f*)(memory + idx);
                __builtin_nontemporal_store(v, (v4f*)(out_mem2 + idx));
            } else {
                const int j = (i4 - Ncopy4) << 2;
                const int li = j >> BLKsh;
                const int k = j & ((1 << BLKsh) - 1);
                const float inv = 1.f / (float)((1 << BLKsh) - 1);
                const float m0 = mask[li], m1 = mask[L + li];
                const v4f ya = *(const v4f*)(y_audio + j);
                v4f r;
                #pragma unroll
                for (int e = 0; e < 4; ++e) {
                    const float fade = (float)(k + e) * inv;
                    r[e] = ya[e] * (m1 * fade + m0 * (1.f - fade));
                }
                *(v4f*)(out_y + j) = r;
            }
        }
        return;
    }

    // ---------------- matvec tile ----------------
    __shared__ float x_lds[512];
    __shared__ float ps[16 * 128];

    const int mb = bid - NMISC;
    const int l = mb >> bplSh;
    const int chunk = mb & ((1 << bplSh) - 1);
    const int f0 = chunk << 9;           // 512 rows per tile

    const int w = tid >> 6;              // wave 0..7: rows [w*64, w*64+64)
    const int par = (tid >> 5) & 1;      // even/odd row within pair
    const int t = tid & 31;              // lane: d-range t*4..t*4+3
    const int rbase = (w << 6) + par;

    // iteration i reads rows rbase+2i -> offset i KiB; 1 KiB/wave-instruction
    const v4f* __restrict__ Wv =
        (const v4f*)(weights + ((size_t)(l * F + f0) << Dsh)) + (rbase << 5) + t;

    v4f pre[8];
    #pragma unroll
    for (int j = 0; j < 8; ++j) pre[j] = Wv[j << 6];

    // ---- x[f0 .. f0+511] into LDS (overlaps prefetch latency) ----
    {
        const int f = f0 + tid;
        const int c = f >> LDsh;
        const int rem = f & (LD - 1);
        const int ll = rem >> Dsh;
        const int dd = rem & (D - 1);
        int row = rec - (*ctx_p) + c;
        if (row < 0) row += n_memory;
        const int dt = (*ctx_p) - c;             // ring distance, 1..ctx
        const float v = (ll == i_act && dt <= lc)
                            ? z_in[dd]
                            : memory[((size_t)row << LDsh) + rem];
        const float cen = center[(size_t)l * F + f];
        x_lds[tid] = tanhf((v - cen) * 0.5f);
    }
    __syncthreads();

    // ---- matvec ----
    v4f acc = (v4f)0.f;
    #pragma unroll
    for (int j = 0; j < 8; ++j) acc += x_lds[rbase + (j << 1)] * pre[j];
    #pragma unroll 8
    for (int i = 8; i < 32; ++i)
        acc += x_lds[rbase + (i << 1)] * Wv[i << 6];

    ((v4f*)&ps[(tid >> 5) << 7])[t] = acc;       // 16 groups x 128
    __syncthreads();

    if (tid < 128) {
        float s = 0.f;
        #pragma unroll
        for (int gg = 0; gg < 16; ++gg) s += ps[(gg << 7) + tid];
        partials[((size_t)mb << 7) + tid] = s;   // coalesced 512B
    }
}

// reduce partials; bias, target_process_inv, clip; write zs and mem2[rec].
__global__ __launch_bounds__(256) void ll_finalize_kernel(
    const float* __restrict__ partials, const float* __restrict__ bias,
    const float* __restrict__ z_min, const float* __restrict__ z_max,
    const float* __restrict__ limit_margin, const float* __restrict__ z_in,
    const int* __restrict__ rec_p, const int* __restrict__ act_p,
    float* __restrict__ out_zs, float* __restrict__ out_mem2,
    int L, int D, int bpl)
{
    const int tid = blockIdx.x * blockDim.x + threadIdx.x;
    if (tid >= L * D) return;
    const int l = tid / D;
    const int d = tid - l * D;

    // 4 independent accumulators, unroll 32 -> >=32 loads in flight (MLP)
    float s0 = 0.f, s1 = 0.f, s2 = 0.f, s3 = 0.f;
    const float* __restrict__ p = partials + ((size_t)l * bpl) * D + d;
    #pragma unroll 8
    for (int c = 0; c < bpl; c += 4) {
        s0 += p[(size_t)(c + 0) * D];
        s1 += p[(size_t)(c + 1) * D];
        s2 += p[(size_t)(c + 2) * D];
        s3 += p[(size_t)(c + 3) * D];
    }
    float z = (s0 + s1) + (s2 + s3) + bias[tid];

    const float hi = 2.f * sqrtf(fmaxf(z, 1.f)) - 1.f;
    const float lo = 1.f - 2.f * sqrtf(fmaxf(-z, 1.f));
    z = (z > 1.f) ? hi : ((z < -1.f) ? lo : z);
    const float zl = z_min[tid] - limit_margin[d];
    const float zh = z_max[tid] + limit_margin[d];
    z = fminf(fmaxf(z, zl), zh);

    const float out = (l == (*act_p - 1)) ? z_in[d] : z;
    out_zs[tid] = out;
    out_mem2[(size_t)(*rec_p) * (L * D) + tid] = out;
}

extern "C" void kernel_launch(void* const* d_in, const int* in_sizes, int n_in,
                              void* d_out, int out_size, void* d_ws, size_t ws_size,
                              hipStream_t stream) {
    const float* memory       = (const float*)d_in[0];
    const float* z_in         = (const float*)d_in[1];
    const float* weights      = (const float*)d_in[2];
    const float* center       = (const float*)d_in[3];
    const float* bias         = (const float*)d_in[4];
    const float* z_min        = (const float*)d_in[5];
    const float* z_max        = (const float*)d_in[6];
    const float* limit_margin = (const float*)d_in[7];
    const float* mask         = (const float*)d_in[8];
    const float* y_audio      = (const float*)d_in[9];
    const int*   rec_p        = (const int*)d_in[10];
    const int*   act_p        = (const int*)d_in[11];
    const int*   lc_p         = (const int*)d_in[12];
    const int*   ctx_p        = (const int*)d_in[13];

    const int D        = in_sizes[1];            // 128
    const int L        = in_sizes[4] / D;        // 8
    const int LD       = L * D;                  // 1024
    const int n_memory = in_sizes[0] / LD;       // 1067
    const int F        = in_sizes[3] / L;        // 65536
    const int BLK      = in_sizes[9] / L;        // 2048

    const int Dsh   = __builtin_ctz(D);          // 7
    const int LDsh  = __builtin_ctz(LD);         // 10
    const int BLKsh = __builtin_ctz(BLK);        // 11
    const int bpl   = F >> 9;                    // 128 blocks per loop
    const int bplSh = __builtin_ctz(bpl);        // 7

    float* out_y    = (float*)d_out;             // [L*BLK]
    float* out_zs   = out_y + (size_t)L * BLK;   // [LD]
    float* out_mem2 = out_zs + LD;               // [n_memory*LD]

    float* partials = (float*)d_ws;              // [L*bpl*128] = 512 KB

    const int grid = NMISC + L * bpl;            // 256 + 1024 = 1280
    ll_main_kernel<<<grid, 512, 0, stream>>>(
        memory, z_in, weights, center, mask, y_audio,
        rec_p, act_p, lc_p, ctx_p,
        partials, out_y, out_mem2,
        L, F, n_memory, BLK, Dsh, LDsh, BLKsh, bplSh);

    ll_finalize_kernel<<<(LD + 255) / 256, 256, 0, stream>>>(
        partials, bias, z_min, z_max, limit_margin, z_in,
        rec_p, act_p, out_zs, out_mem2, L, D, bpl);
}